// Round 1
// baseline (1281.551 us; speedup 1.0000x reference)
//
#include <hip/hip_runtime.h>
#include <hip/hip_bf16.h>
#include <cstddef>

// Problem dims
#define TT 65536
#define HD 256
#define NK (TT - 1)      // scan steps
#define NCH 256          // chunks
#define CLEN 256         // chunk length
#define BT 32            // rows per block in MLP kernel

// d_out offsets (floats): log_alpha, log_beta, log_trs, log_pis, entropy
#define OFF_ALPHA 0
#define OFF_BETA  (TT * 16)
#define OFF_TRS   (2 * TT * 16)
#define OFF_PIS   (OFF_TRS + NK * 256)
#define OFF_ENT   (OFF_PIS + TT * 16)

__device__ __forceinline__ void lse_merge(float& m, float& s, float mo, float so) {
  float mm = fmaxf(m, mo);
  s = s * __expf(m - mm) + so * __expf(mo - mm);
  m = mm;
}

// ---------------- Kernel 1: fused MLPs ----------------
// Per block: 32 rows. Policy MLP -> log_pis (written to out).
// Option MLP -> raw logits cols 0..255 written into out[log_trs] slot (t>=1),
// t=0 row16 (cols 256..271) -> ws_logtr0.

__device__ __forceinline__ void layer_s_to_h(const float* __restrict__ s, int r0,
                                             const float* __restrict__ W,
                                             const float* __restrict__ b,
                                             float (*hout)[HD], int tid)
{
  float acc[BT];
  #pragma unroll
  for (int r = 0; r < BT; ++r) acc[r] = 0.f;
  for (int k = 0; k < 64; k += 4) {
    float w0 = W[(k + 0) * HD + tid];
    float w1 = W[(k + 1) * HD + tid];
    float w2 = W[(k + 2) * HD + tid];
    float w3 = W[(k + 3) * HD + tid];
    #pragma unroll
    for (int r = 0; r < BT; ++r) {
      float4 sv = *reinterpret_cast<const float4*>(&s[(size_t)(r0 + r) * 64 + k]);
      acc[r] = fmaf(sv.w, w3, fmaf(sv.z, w2, fmaf(sv.y, w1, fmaf(sv.x, w0, acc[r]))));
    }
  }
  float bb = b[tid];
  #pragma unroll
  for (int r = 0; r < BT; ++r) hout[r][tid] = fmaxf(acc[r] + bb, 0.f);
  __syncthreads();
}

// hin may alias hout (barrier separates all reads from writes)
__device__ __forceinline__ void layer_h_to_h(const float* __restrict__ W,
                                             const float* __restrict__ b,
                                             float (*hin)[HD],
                                             float (*hout)[HD], int tid)
{
  float acc[BT];
  #pragma unroll
  for (int r = 0; r < BT; ++r) acc[r] = 0.f;
  for (int k = 0; k < HD; k += 4) {
    float w0 = W[(k + 0) * HD + tid];
    float w1 = W[(k + 1) * HD + tid];
    float w2 = W[(k + 2) * HD + tid];
    float w3 = W[(k + 3) * HD + tid];
    #pragma unroll
    for (int r = 0; r < BT; ++r) {
      float4 hv = *reinterpret_cast<const float4*>(&hin[r][k]);
      acc[r] = fmaf(hv.w, w3, fmaf(hv.z, w2, fmaf(hv.y, w1, fmaf(hv.x, w0, acc[r]))));
    }
  }
  float bb = b[tid];
  __syncthreads();  // all reads of hin done before overwrite
  #pragma unroll
  for (int r = 0; r < BT; ++r) hout[r][tid] = fmaxf(acc[r] + bb, 0.f);
  __syncthreads();
}

extern "C" __global__ void __launch_bounds__(256)
k_mlp(const float* __restrict__ s, const float* __restrict__ a_arr,
      const float* __restrict__ pW1, const float* __restrict__ pb1,
      const float* __restrict__ pW2, const float* __restrict__ pb2,
      const float* __restrict__ pW3, const float* __restrict__ pb3,
      const float* __restrict__ oW1, const float* __restrict__ ob1,
      const float* __restrict__ oW2, const float* __restrict__ ob2,
      const float* __restrict__ oW3, const float* __restrict__ ob3,
      const float* __restrict__ a_log_std,
      float* __restrict__ out, float* __restrict__ ws_logtr0)
{
  __shared__ float hA[BT][HD];  // 32 KB
  __shared__ float hB[BT][HD];  // 32 KB
  const int tid = threadIdx.x;
  const int r0 = blockIdx.x * BT;

  // ---- policy MLP ----
  layer_s_to_h(s, r0, pW1, pb1, hA, tid);
  layer_h_to_h(pW2, pb2, hA, hA, tid);  // h2p now in hA

  // ---- mean -> log_pis (summed over DIM_A=8 via in-wave shfl) ----
  {
    const int col = tid & 127, half = tid >> 7;   // col = c*8 + a
    const int a_idx = col & 7, c_idx = col >> 3;
    float accm[16];
    #pragma unroll
    for (int r = 0; r < 16; ++r) accm[r] = 0.f;
    for (int k = 0; k < HD; k += 4) {
      float w0 = pW3[(k + 0) * 128 + col];
      float w1 = pW3[(k + 1) * 128 + col];
      float w2 = pW3[(k + 2) * 128 + col];
      float w3 = pW3[(k + 3) * 128 + col];
      #pragma unroll
      for (int r = 0; r < 16; ++r) {
        float4 hv = *reinterpret_cast<const float4*>(&hA[half * 16 + r][k]);
        accm[r] = fmaf(hv.w, w3, fmaf(hv.z, w2, fmaf(hv.y, w1, fmaf(hv.x, w0, accm[r]))));
      }
    }
    float bb = pb3[col];
    float th = tanhf(a_log_std[a_idx]);
    float logstd = -5.0f + 3.5f * (th + 1.0f);
    float inv_std = __expf(-logstd);
    const float cterm = -logstd - 0.91893853320467274f;  // -logstd - 0.5*log(2pi)
    #pragma unroll
    for (int r = 0; r < 16; ++r) {
      int t = r0 + half * 16 + r;
      float m = accm[r] + bb;
      m = fminf(fmaxf(m, -10.f), 10.f);
      float z = (a_arr[(size_t)t * 8 + a_idx] - m) * inv_std;
      float term = fmaf(-0.5f * z, z, cterm);
      term += __shfl_xor(term, 1);
      term += __shfl_xor(term, 2);
      term += __shfl_xor(term, 4);
      if (a_idx == 0) out[OFF_PIS + (size_t)t * 16 + c_idx] = term;
    }
  }
  __syncthreads();  // mean reads of hA done before option MLP overwrites

  // ---- option MLP ----
  layer_s_to_h(s, r0, oW1, ob1, hA, tid);
  layer_h_to_h(oW2, ob2, hA, hB, tid);  // h2o in hB

  // ---- logits cols 0..255 -> raw into log_trs slot (t >= 1) ----
  {
    float acc[BT];
    #pragma unroll
    for (int r = 0; r < BT; ++r) acc[r] = 0.f;
    for (int k = 0; k < HD; k += 4) {
      float w0 = oW3[(k + 0) * 272 + tid];
      float w1 = oW3[(k + 1) * 272 + tid];
      float w2 = oW3[(k + 2) * 272 + tid];
      float w3 = oW3[(k + 3) * 272 + tid];
      #pragma unroll
      for (int r = 0; r < BT; ++r) {
        float4 hv = *reinterpret_cast<const float4*>(&hB[r][k]);
        acc[r] = fmaf(hv.w, w3, fmaf(hv.z, w2, fmaf(hv.y, w1, fmaf(hv.x, w0, acc[r]))));
      }
    }
    float bb = ob3[tid];
    #pragma unroll
    for (int r = 0; r < BT; ++r) {
      int t = r0 + r;
      if (t >= 1) out[OFF_TRS + (size_t)(t - 1) * 256 + tid] = acc[r] + bb;
    }
  }

  // ---- t=0, row 16 (cols 256..271) -> ws_logtr0 ----
  if (blockIdx.x == 0 && tid < 16) {
    const int colx = 256 + tid;
    float a2 = 0.f;
    for (int k = 0; k < HD; ++k) a2 = fmaf(hB[0][k], oW3[(size_t)k * 272 + colx], a2);
    ws_logtr0[tid] = a2 + ob3[colx];
  }
}

// ---------------- Kernel 2: in-place log_softmax + entropy + a0 ----------------
extern "C" __global__ void __launch_bounds__(256)
k_softmax(float* __restrict__ out, const float* __restrict__ ws_logtr0, float* __restrict__ ws_a0)
{
  const int row = blockIdx.x * 256 + threadIdx.x;
  if (row < NK * 16) {
    float* p = out + OFF_TRS + (size_t)row * 16;
    float x[16];
    #pragma unroll
    for (int q = 0; q < 16; q += 4) {
      float4 v = *reinterpret_cast<float4*>(p + q);
      x[q] = v.x; x[q + 1] = v.y; x[q + 2] = v.z; x[q + 3] = v.w;
    }
    float mx = x[0];
    #pragma unroll
    for (int q = 1; q < 16; ++q) mx = fmaxf(mx, x[q]);
    float sum = 0.f;
    float e[16];
    #pragma unroll
    for (int q = 0; q < 16; ++q) { e[q] = __expf(x[q] - mx); sum += e[q]; }
    float ls = mx + __logf(sum);
    float inv = 1.0f / sum;
    float ent = 0.f;
    #pragma unroll
    for (int q = 0; q < 16; ++q) { x[q] -= ls; ent = fmaf(x[q], e[q], ent); }
    #pragma unroll
    for (int q = 0; q < 16; q += 4) {
      float4 v = make_float4(x[q], x[q + 1], x[q + 2], x[q + 3]);
      *reinterpret_cast<float4*>(p + q) = v;
    }
    out[OFF_ENT + row] = -ent * inv;
  }
  if (blockIdx.x == 0 && threadIdx.x < 16) {
    const int j = threadIdx.x;
    float mx = ws_logtr0[0];
    for (int q = 1; q < 16; ++q) mx = fmaxf(mx, ws_logtr0[q]);
    float sum = 0.f;
    for (int q = 0; q < 16; ++q) sum += __expf(ws_logtr0[q] - mx);
    float ls = mx + __logf(sum);
    float a0 = ws_logtr0[j] - ls + out[OFF_PIS + j];  // log_tr0 + log_pis[0]
    ws_a0[j] = a0;
    out[OFF_ALPHA + j] = a0;
    out[OFF_BETA + (size_t)(TT - 1) * 16 + j] = 0.f;
  }
}

// ---------------- Kernel 3: per-chunk folded transition matrices ----------------
// G[k][i][j] = log_trs[k][i][j] + log_pis[k+1][j]; M_c = G[k0] (x) ... (x) G[k1]
extern "C" __global__ void __launch_bounds__(256)
k_chunk(const float* __restrict__ out, float* __restrict__ Ms, float* __restrict__ MsT)
{
  __shared__ float Msh[256];
  __shared__ float Gsh[256];
  const int c = blockIdx.x, tid = threadIdx.x;
  const int i = tid >> 4, j = tid & 15;
  const int k0 = c * CLEN;
  const int k1 = min(k0 + CLEN, NK) - 1;
  const float* trs = out + OFF_TRS;
  const float* pis = out + OFF_PIS;
  float mij = trs[k0 * 256 + tid] + pis[(k0 + 1) * 16 + j];
  for (int k = k0 + 1; k <= k1; ++k) {
    Msh[tid] = mij;
    Gsh[tid] = trs[k * 256 + tid] + pis[(k + 1) * 16 + j];
    __syncthreads();
    float t[16];
    #pragma unroll
    for (int q = 0; q < 16; ++q) t[q] = Msh[i * 16 + q] + Gsh[q * 16 + j];
    float mx = t[0];
    #pragma unroll
    for (int q = 1; q < 16; ++q) mx = fmaxf(mx, t[q]);
    float ssum = 0.f;
    #pragma unroll
    for (int q = 0; q < 16; ++q) ssum += __expf(t[q] - mx);
    mij = mx + __logf(ssum);
    __syncthreads();
  }
  Ms[c * 256 + tid] = mij;
  MsT[c * 256 + j * 16 + i] = mij;  // transposed copy for the alpha direction
}

// ---------------- Kernel 4: boundary scan (1 wave per direction) ----------------
extern "C" __global__ void __launch_bounds__(64)
k_boundary(const float* __restrict__ Ms, const float* __restrict__ MsT,
           const float* __restrict__ a0, float* __restrict__ bA, float* __restrict__ bB)
{
  const int l = threadIdx.x;
  const int g = l >> 4;
  if (blockIdx.x == 0) {
    // alpha: v_{c+1} = v_c (x) M_c  (row-vector)
    const int j = l & 15;
    float v0 = a0[g * 4 + 0], v1 = a0[g * 4 + 1], v2 = a0[g * 4 + 2], v3 = a0[g * 4 + 3];
    if (l < 16) bA[l] = a0[l];
    for (int c = 0; c < NCH; ++c) {
      float4 mr = *reinterpret_cast<const float4*>(&MsT[c * 256 + j * 16 + g * 4]);
      float t0 = v0 + mr.x, t1 = v1 + mr.y, t2 = v2 + mr.z, t3 = v3 + mr.w;
      float m = fmaxf(fmaxf(t0, t1), fmaxf(t2, t3));
      float ssum = __expf(t0 - m) + __expf(t1 - m) + __expf(t2 - m) + __expf(t3 - m);
      lse_merge(m, ssum, __shfl_xor(m, 16), __shfl_xor(ssum, 16));
      lse_merge(m, ssum, __shfl_xor(m, 32), __shfl_xor(ssum, 32));
      float nv = m + __logf(ssum);
      if (c + 1 < NCH && l < 16) bA[(c + 1) * 16 + l] = nv;
      v0 = __shfl(nv, g * 4 + 0); v1 = __shfl(nv, g * 4 + 1);
      v2 = __shfl(nv, g * 4 + 2); v3 = __shfl(nv, g * 4 + 3);
    }
  } else {
    // beta: w_c = M_c (x) w_{c+1}  (column-vector), bB[c] = right-boundary of chunk c
    const int i = l & 15;
    float w0 = 0.f, w1 = 0.f, w2 = 0.f, w3 = 0.f;
    if (l < 16) bB[(NCH - 1) * 16 + l] = 0.f;
    for (int c = NCH - 1; c >= 0; --c) {
      float4 mr = *reinterpret_cast<const float4*>(&Ms[c * 256 + i * 16 + g * 4]);
      float t0 = w0 + mr.x, t1 = w1 + mr.y, t2 = w2 + mr.z, t3 = w3 + mr.w;
      float m = fmaxf(fmaxf(t0, t1), fmaxf(t2, t3));
      float ssum = __expf(t0 - m) + __expf(t1 - m) + __expf(t2 - m) + __expf(t3 - m);
      lse_merge(m, ssum, __shfl_xor(m, 16), __shfl_xor(ssum, 16));
      lse_merge(m, ssum, __shfl_xor(m, 32), __shfl_xor(ssum, 32));
      float nw = m + __logf(ssum);
      if (c > 0 && l < 16) bB[(c - 1) * 16 + l] = nw;
      w0 = __shfl(nw, g * 4 + 0); w1 = __shfl(nw, g * 4 + 1);
      w2 = __shfl(nw, g * 4 + 2); w3 = __shfl(nw, g * 4 + 3);
    }
  }
}

// ---------------- Kernel 5: per-chunk replay, emit all alpha/beta rows ----------------
extern "C" __global__ void __launch_bounds__(64)
k_replay(float* __restrict__ out, const float* __restrict__ bA, const float* __restrict__ bB)
{
  const int l = threadIdx.x;
  const int g = l >> 4;
  const float* trs = out + OFF_TRS;
  const float* pis = out + OFF_PIS;
  if (blockIdx.x < NCH) {
    const int c = blockIdx.x;
    const int k0 = c * CLEN, k1 = min(k0 + CLEN, NK) - 1;
    const int j = l & 15;
    float v0 = bA[c * 16 + g * 4 + 0], v1 = bA[c * 16 + g * 4 + 1];
    float v2 = bA[c * 16 + g * 4 + 2], v3 = bA[c * 16 + g * 4 + 3];
    for (int k = k0; k <= k1; ++k) {
      const float* row = trs + (size_t)k * 256;
      float t0 = v0 + row[(g * 4 + 0) * 16 + j];
      float t1 = v1 + row[(g * 4 + 1) * 16 + j];
      float t2 = v2 + row[(g * 4 + 2) * 16 + j];
      float t3 = v3 + row[(g * 4 + 3) * 16 + j];
      float m = fmaxf(fmaxf(t0, t1), fmaxf(t2, t3));
      float ssum = __expf(t0 - m) + __expf(t1 - m) + __expf(t2 - m) + __expf(t3 - m);
      lse_merge(m, ssum, __shfl_xor(m, 16), __shfl_xor(ssum, 16));
      lse_merge(m, ssum, __shfl_xor(m, 32), __shfl_xor(ssum, 32));
      float nv = m + __logf(ssum) + pis[(k + 1) * 16 + j];
      if (l < 16) out[OFF_ALPHA + (size_t)(k + 1) * 16 + l] = nv;
      v0 = __shfl(nv, g * 4 + 0); v1 = __shfl(nv, g * 4 + 1);
      v2 = __shfl(nv, g * 4 + 2); v3 = __shfl(nv, g * 4 + 3);
    }
  } else {
    const int c = blockIdx.x - NCH;
    const int k0 = c * CLEN, k1 = min(k0 + CLEN, NK) - 1;
    const int i = l & 15;
    float w0 = bB[c * 16 + g * 4 + 0], w1 = bB[c * 16 + g * 4 + 1];
    float w2 = bB[c * 16 + g * 4 + 2], w3 = bB[c * 16 + g * 4 + 3];
    for (int k = k1; k >= k0; --k) {
      float4 tr4 = *reinterpret_cast<const float4*>(&trs[(size_t)k * 256 + i * 16 + g * 4]);
      float4 pi4 = *reinterpret_cast<const float4*>(&pis[(size_t)(k + 1) * 16 + g * 4]);
      float t0 = w0 + tr4.x + pi4.x;
      float t1 = w1 + tr4.y + pi4.y;
      float t2 = w2 + tr4.z + pi4.z;
      float t3 = w3 + tr4.w + pi4.w;
      float m = fmaxf(fmaxf(t0, t1), fmaxf(t2, t3));
      float ssum = __expf(t0 - m) + __expf(t1 - m) + __expf(t2 - m) + __expf(t3 - m);
      lse_merge(m, ssum, __shfl_xor(m, 16), __shfl_xor(ssum, 16));
      lse_merge(m, ssum, __shfl_xor(m, 32), __shfl_xor(ssum, 32));
      float nw = m + __logf(ssum);
      if (l < 16) out[OFF_BETA + (size_t)k * 16 + l] = nw;
      w0 = __shfl(nw, g * 4 + 0); w1 = __shfl(nw, g * 4 + 1);
      w2 = __shfl(nw, g * 4 + 2); w3 = __shfl(nw, g * 4 + 3);
    }
  }
}

extern "C" void kernel_launch(void* const* d_in, const int* in_sizes, int n_in,
                              void* d_out, int out_size, void* d_ws, size_t ws_size,
                              hipStream_t stream)
{
  const float* s     = (const float*)d_in[0];
  const float* a_arr = (const float*)d_in[1];
  const float* pW1 = (const float*)d_in[2];
  const float* pb1 = (const float*)d_in[3];
  const float* pW2 = (const float*)d_in[4];
  const float* pb2 = (const float*)d_in[5];
  const float* pW3 = (const float*)d_in[6];
  const float* pb3 = (const float*)d_in[7];
  const float* oW1 = (const float*)d_in[8];
  const float* ob1 = (const float*)d_in[9];
  const float* oW2 = (const float*)d_in[10];
  const float* ob2 = (const float*)d_in[11];
  const float* oW3 = (const float*)d_in[12];
  const float* ob3 = (const float*)d_in[13];
  const float* a_log_std = (const float*)d_in[14];
  float* out = (float*)d_out;

  // workspace layout (floats): Ms[65536] | MsT[65536] | bA[4096] | bB[4096] | a0[16] | logtr0[16]
  float* w   = (float*)d_ws;
  float* Ms  = w;
  float* MsT = w + 65536;
  float* bA  = w + 131072;
  float* bB  = w + 135168;
  float* a0  = w + 139264;
  float* lt0 = w + 139280;

  k_mlp<<<TT / BT, 256, 0, stream>>>(s, a_arr, pW1, pb1, pW2, pb2, pW3, pb3,
                                     oW1, ob1, oW2, ob2, oW3, ob3, a_log_std, out, lt0);
  k_softmax<<<(NK * 16 + 255) / 256, 256, 0, stream>>>(out, lt0, a0);
  k_chunk<<<NCH, 256, 0, stream>>>(out, Ms, MsT);
  k_boundary<<<2, 64, 0, stream>>>(Ms, MsT, a0, bA, bB);
  k_replay<<<2 * NCH, 64, 0, stream>>>(out, bA, bB);
}

// Round 3
// 1087.478 us; speedup vs baseline: 1.1785x; 1.1785x over previous
//
#include <hip/hip_runtime.h>
#include <cstddef>

// Problem dims
#define TT 65536
#define NK (TT - 1)      // scan steps
#define NCH 256          // chunks
#define CLEN 256         // chunk length

// d_out offsets (floats): log_alpha, log_beta, log_trs, log_pis, entropy
#define OFF_ALPHA 0
#define OFF_BETA  (TT * 16)
#define OFF_TRS   (2 * TT * 16)
#define OFF_PIS   (OFF_TRS + NK * 256)
#define OFF_ENT   (OFF_PIS + TT * 16)

// bf16 weight plane element offsets (ushort units), layout [n][k]
#define W_PW1 0        // 256 x 64
#define W_PW2 16384    // 256 x 256
#define W_PW3 81920    // 128 x 256
#define W_OW1 114688   // 256 x 64
#define W_OW2 131072   // 256 x 256
#define W_OW3 196608   // 272 x 256
#define W_TOTAL 266240
#define WS_WEIGHT_OFF 557184   // bytes: scan float region sits below this

typedef __attribute__((ext_vector_type(8))) short bf16x8;
typedef __attribute__((ext_vector_type(4))) float f32x4;
typedef __attribute__((ext_vector_type(4))) unsigned short us4;

__device__ __forceinline__ unsigned short bf16_rne(float x) {
  unsigned int u = __float_as_uint(x);
  unsigned int r = u + 0x7FFFu + ((u >> 16) & 1u);
  return (unsigned short)(r >> 16);
}
__device__ __forceinline__ float bf16_f(unsigned short h) {
  return __uint_as_float(((unsigned int)h) << 16);
}

__device__ __forceinline__ void lse_merge(float& m, float& s, float mo, float so) {
  float mm = fmaxf(m, mo);
  s = s * __expf(m - mm) + so * __expf(mo - mm);
  m = mm;
}

// ---------------- Kernel 0: weight convert fp32 -> bf16 hi/lo planes, [n][k] ----------------
extern "C" __global__ void __launch_bounds__(256)
k_wconv(const float* __restrict__ pW1, const float* __restrict__ pW2,
        const float* __restrict__ pW3, const float* __restrict__ oW1,
        const float* __restrict__ oW2, const float* __restrict__ oW3,
        unsigned short* __restrict__ wbase)
{
  int e = blockIdx.x * 256 + threadIdx.x;
  if (e >= W_TOTAL) return;
  float x;
  if (e < W_PW2)      { int l = e - W_PW1; int n = l >> 6; int k = l & 63;  x = pW1[k * 256 + n]; }
  else if (e < W_PW3) { int l = e - W_PW2; int n = l >> 8; int k = l & 255; x = pW2[k * 256 + n]; }
  else if (e < W_OW1) { int l = e - W_PW3; int n = l >> 8; int k = l & 255; x = pW3[k * 128 + n]; }
  else if (e < W_OW2) { int l = e - W_OW1; int n = l >> 6; int k = l & 63;  x = oW1[k * 256 + n]; }
  else if (e < W_OW3) { int l = e - W_OW2; int n = l >> 8; int k = l & 255; x = oW2[k * 256 + n]; }
  else                { int l = e - W_OW3; int n = l >> 8; int k = l & 255; x = oW3[k * 272 + n]; }
  unsigned short h = bf16_rne(x);
  wbase[e] = h;
  wbase[W_TOTAL + e] = bf16_rne(x - bf16_f(h));
}

// ---------------- Kernel 1: fused MLPs via split-bf16 MFMA ----------------
// Computes H^T = W^T * X^T per 16x16x32 MFMA tile.
// A-frag = W[n][k] (8 contiguous k), B-frag = X[sample][k] (8 contiguous k),
// D: sample = lane&15-col, n = (lane>>4)*4 + reg. Wave w owns samples w*16..w*16+15.

template<int K, int NT>
__device__ __forceinline__ void gemm_layer(const unsigned short* __restrict__ Wh,
                                           const unsigned short* __restrict__ Wl,
                                           const unsigned short* Xh,
                                           const unsigned short* Xl,
                                           int sample, int l15, int kb, f32x4* acc)
{
  #pragma unroll
  for (int nt = 0; nt < NT; ++nt) acc[nt] = (f32x4){0.f, 0.f, 0.f, 0.f};
  const int sw = (sample & 7) << 3;
  #pragma unroll
  for (int ks = 0; ks < K / 32; ++ks) {
    const int kk = ks * 32 + kb * 8;
    bf16x8 xh = *(const bf16x8*)&Xh[sample * K + (kk ^ sw)];
    bf16x8 xl = *(const bf16x8*)&Xl[sample * K + (kk ^ sw)];
    #pragma unroll
    for (int nt = 0; nt < NT; ++nt) {
      const int n = nt * 16 + l15;
      bf16x8 wh = *(const bf16x8*)&Wh[n * K + kk];
      bf16x8 wl = *(const bf16x8*)&Wl[n * K + kk];
      acc[nt] = __builtin_amdgcn_mfma_f32_16x16x32_bf16(wh, xh, acc[nt], 0, 0, 0);
      acc[nt] = __builtin_amdgcn_mfma_f32_16x16x32_bf16(wh, xl, acc[nt], 0, 0, 0);
      acc[nt] = __builtin_amdgcn_mfma_f32_16x16x32_bf16(wl, xh, acc[nt], 0, 0, 0);
    }
  }
}

template<int NT>
__device__ __forceinline__ void relu_store(const f32x4* acc, const float* __restrict__ bias,
                                           unsigned short* Xh, unsigned short* Xl,
                                           int sample, int kb)
{
  const int sw = (sample & 7) << 3;
  #pragma unroll
  for (int nt = 0; nt < NT; ++nt) {
    const int n0 = nt * 16 + kb * 4;
    float4 b4 = *(const float4*)&bias[n0];
    us4 vh, vl;
    #pragma unroll
    for (int r = 0; r < 4; ++r) {
      float h = acc[nt][r] + (&b4.x)[r];
      h = fmaxf(h, 0.f);
      unsigned short hh = bf16_rne(h);
      vh[r] = hh;
      vl[r] = bf16_rne(h - bf16_f(hh));
    }
    *(us4*)&Xh[sample * 256 + (n0 ^ sw)] = vh;
    *(us4*)&Xl[sample * 256 + (n0 ^ sw)] = vl;
  }
}

extern "C" __global__ void __launch_bounds__(256, 2)
k_mlp(const float* __restrict__ s, const float* __restrict__ a_arr,
      const float* __restrict__ pb1, const float* __restrict__ pb2,
      const float* __restrict__ pb3, const float* __restrict__ ob1,
      const float* __restrict__ ob2, const float* __restrict__ ob3,
      const float* __restrict__ a_log_std,
      const unsigned short* __restrict__ wbase,
      float* __restrict__ out, float* __restrict__ ws_logtr0)
{
  __shared__ __align__(16) unsigned short ShS[64 * 64];    // 8 KB
  __shared__ __align__(16) unsigned short SlS[64 * 64];    // 8 KB
  __shared__ __align__(16) unsigned short XhS[64 * 256];   // 32 KB
  __shared__ __align__(16) unsigned short XlS[64 * 256];   // 32 KB

  const int tid = threadIdx.x;
  const int r0 = blockIdx.x * 64;
  const int w = tid >> 6, lane = tid & 63;
  const int l15 = lane & 15, kb = lane >> 4;
  const int sample = w * 16 + l15;
  const int t = r0 + sample;

  // ---- stage s -> Sh/Sl (bf16 hi/lo, XOR-swizzled rows) ----
  #pragma unroll
  for (int q = 0; q < 4; ++q) {
    int f4 = q * 256 + tid;
    int e = f4 * 4;
    int row = e >> 6, col = e & 63;
    float4 v = *(const float4*)&s[(size_t)(r0 + row) * 64 + col];
    us4 vh, vl;
    #pragma unroll
    for (int r = 0; r < 4; ++r) {
      float x = (&v.x)[r];
      unsigned short hh = bf16_rne(x);
      vh[r] = hh;
      vl[r] = bf16_rne(x - bf16_f(hh));
    }
    int cs = col ^ ((row & 7) << 3);
    *(us4*)&ShS[row * 64 + cs] = vh;
    *(us4*)&SlS[row * 64 + cs] = vl;
  }
  __syncthreads();   // only barrier: each wave touches only its own 16 rows afterwards

  f32x4 acc[17];
  const unsigned short* Whi = wbase;
  const unsigned short* Wlo = wbase + W_TOTAL;

  // ---- policy MLP ----
  gemm_layer<64, 16>(Whi + W_PW1, Wlo + W_PW1, ShS, SlS, sample, l15, kb, acc);
  relu_store<16>(acc, pb1, XhS, XlS, sample, kb);
  gemm_layer<256, 16>(Whi + W_PW2, Wlo + W_PW2, XhS, XlS, sample, l15, kb, acc);
  relu_store<16>(acc, pb2, XhS, XlS, sample, kb);
  gemm_layer<256, 8>(Whi + W_PW3, Wlo + W_PW3, XhS, XlS, sample, l15, kb, acc);

  // ---- mean -> log_pis ----
  {
    const int a0 = (kb & 1) * 4;
    float4 av = *(const float4*)&a_arr[(size_t)t * 8 + a0];
    float ist[4], ct[4];
    #pragma unroll
    for (int r = 0; r < 4; ++r) {
      float th = tanhf(a_log_std[a0 + r]);
      float logstd = -5.0f + 3.5f * (th + 1.0f);
      ist[r] = __expf(-logstd);
      ct[r] = -logstd - 0.91893853320467274f;  // -logstd - 0.5*log(2pi)
    }
    #pragma unroll
    for (int nt = 0; nt < 8; ++nt) {
      float4 b4 = *(const float4*)&pb3[nt * 16 + kb * 4];
      float s4 = 0.f;
      #pragma unroll
      for (int r = 0; r < 4; ++r) {
        float m = acc[nt][r] + (&b4.x)[r];
        m = fminf(fmaxf(m, -10.f), 10.f);
        float z = ((&av.x)[r] - m) * ist[r];
        s4 += fmaf(-0.5f * z, z, ct[r]);
      }
      s4 += __shfl_xor(s4, 16);   // partner holds the other 4 of this c's 8 a-dims
      if (!(kb & 1)) out[OFF_PIS + (size_t)t * 16 + nt * 2 + (kb >> 1)] = s4;
    }
  }

  // ---- option MLP ----
  gemm_layer<64, 16>(Whi + W_OW1, Wlo + W_OW1, ShS, SlS, sample, l15, kb, acc);
  relu_store<16>(acc, ob1, XhS, XlS, sample, kb);
  gemm_layer<256, 16>(Whi + W_OW2, Wlo + W_OW2, XhS, XlS, sample, l15, kb, acc);
  relu_store<16>(acc, ob2, XhS, XlS, sample, kb);
  gemm_layer<256, 17>(Whi + W_OW3, Wlo + W_OW3, XhS, XlS, sample, l15, kb, acc);

  // ---- raw logits cols 0..255 -> log_trs slot (t>=1) ----
  #pragma unroll
  for (int nt = 0; nt < 16; ++nt) {
    const int n0 = nt * 16 + kb * 4;
    float4 b4 = *(const float4*)&ob3[n0];
    float4 v;
    #pragma unroll
    for (int r = 0; r < 4; ++r) (&v.x)[r] = acc[nt][r] + (&b4.x)[r];
    if (t >= 1) *(float4*)&out[OFF_TRS + (size_t)(t - 1) * 256 + n0] = v;
  }
  // ---- t=0 cols 256..271 -> ws_logtr0 ----
  if (t == 0) {
    const int n0 = 256 + kb * 4;
    float4 b4 = *(const float4*)&ob3[n0];
    float4 v;
    #pragma unroll
    for (int r = 0; r < 4; ++r) (&v.x)[r] = acc[16][r] + (&b4.x)[r];
    *(float4*)&ws_logtr0[kb * 4] = v;
  }
}

// ---------------- Kernel 2: in-place log_softmax + entropy + a0 ----------------
extern "C" __global__ void __launch_bounds__(256)
k_softmax(float* __restrict__ out, const float* __restrict__ ws_logtr0, float* __restrict__ ws_a0)
{
  const int row = blockIdx.x * 256 + threadIdx.x;
  if (row < NK * 16) {
    float* p = out + OFF_TRS + (size_t)row * 16;
    float x[16];
    #pragma unroll
    for (int q = 0; q < 16; q += 4) {
      float4 v = *reinterpret_cast<float4*>(p + q);
      x[q] = v.x; x[q + 1] = v.y; x[q + 2] = v.z; x[q + 3] = v.w;
    }
    float mx = x[0];
    #pragma unroll
    for (int q = 1; q < 16; ++q) mx = fmaxf(mx, x[q]);
    float sum = 0.f;
    float e[16];
    #pragma unroll
    for (int q = 0; q < 16; ++q) { e[q] = __expf(x[q] - mx); sum += e[q]; }
    float ls = mx + __logf(sum);
    float inv = 1.0f / sum;
    float ent = 0.f;
    #pragma unroll
    for (int q = 0; q < 16; ++q) { x[q] -= ls; ent = fmaf(x[q], e[q], ent); }
    #pragma unroll
    for (int q = 0; q < 16; q += 4) {
      float4 v = make_float4(x[q], x[q + 1], x[q + 2], x[q + 3]);
      *reinterpret_cast<float4*>(p + q) = v;
    }
    out[OFF_ENT + row] = -ent * inv;
  }
  if (blockIdx.x == 0 && threadIdx.x < 16) {
    const int j = threadIdx.x;
    float mx = ws_logtr0[0];
    for (int q = 1; q < 16; ++q) mx = fmaxf(mx, ws_logtr0[q]);
    float sum = 0.f;
    for (int q = 0; q < 16; ++q) sum += __expf(ws_logtr0[q] - mx);
    float ls = mx + __logf(sum);
    float a0 = ws_logtr0[j] - ls + out[OFF_PIS + j];  // log_tr0 + log_pis[0]
    ws_a0[j] = a0;
    out[OFF_ALPHA + j] = a0;
    out[OFF_BETA + (size_t)(TT - 1) * 16 + j] = 0.f;
  }
}

// ---------------- Kernel 3: per-chunk folded transition matrices (prefetched) ----------------
extern "C" __global__ void __launch_bounds__(256)
k_chunk(const float* __restrict__ out, float* __restrict__ Ms, float* __restrict__ MsT)
{
  __shared__ float Msh[256];
  __shared__ float Gsh[256];
  const int c = blockIdx.x, tid = threadIdx.x;
  const int i = tid >> 4, j = tid & 15;
  const int k0 = c * CLEN;
  const int k1 = min(k0 + CLEN, NK) - 1;
  const float* trs = out + OFF_TRS;
  const float* pis = out + OFF_PIS;
  float mij = trs[(size_t)k0 * 256 + tid] + pis[(size_t)(k0 + 1) * 16 + j];
  float gn = 0.f;
  if (k0 + 1 <= k1) gn = trs[(size_t)(k0 + 1) * 256 + tid] + pis[(size_t)(k0 + 2) * 16 + j];
  for (int k = k0 + 1; k <= k1; ++k) {
    Msh[tid] = mij;
    Gsh[tid] = gn;
    __syncthreads();
    float gnx = 0.f;
    if (k + 1 <= k1) gnx = trs[(size_t)(k + 1) * 256 + tid] + pis[(size_t)(k + 2) * 16 + j];
    float tq[16];
    #pragma unroll
    for (int q = 0; q < 16; ++q) tq[q] = Msh[i * 16 + q] + Gsh[q * 16 + j];
    float mx = tq[0];
    #pragma unroll
    for (int q = 1; q < 16; ++q) mx = fmaxf(mx, tq[q]);
    float ssum = 0.f;
    #pragma unroll
    for (int q = 0; q < 16; ++q) ssum += __expf(tq[q] - mx);
    mij = mx + __logf(ssum);
    __syncthreads();
    gn = gnx;
  }
  Ms[c * 256 + tid] = mij;
  MsT[c * 256 + j * 16 + i] = mij;
}

// ---------------- Kernel 4: boundary scan (1 wave per direction) ----------------
extern "C" __global__ void __launch_bounds__(64)
k_boundary(const float* __restrict__ Ms, const float* __restrict__ MsT,
           const float* __restrict__ a0, float* __restrict__ bA, float* __restrict__ bB)
{
  const int l = threadIdx.x;
  const int g = l >> 4;
  if (blockIdx.x == 0) {
    const int j = l & 15;
    float v0 = a0[g * 4 + 0], v1 = a0[g * 4 + 1], v2 = a0[g * 4 + 2], v3 = a0[g * 4 + 3];
    if (l < 16) bA[l] = a0[l];
    for (int c = 0; c < NCH; ++c) {
      float4 mr = *reinterpret_cast<const float4*>(&MsT[c * 256 + j * 16 + g * 4]);
      float t0 = v0 + mr.x, t1 = v1 + mr.y, t2 = v2 + mr.z, t3 = v3 + mr.w;
      float m = fmaxf(fmaxf(t0, t1), fmaxf(t2, t3));
      float ssum = __expf(t0 - m) + __expf(t1 - m) + __expf(t2 - m) + __expf(t3 - m);
      lse_merge(m, ssum, __shfl_xor(m, 16), __shfl_xor(ssum, 16));
      lse_merge(m, ssum, __shfl_xor(m, 32), __shfl_xor(ssum, 32));
      float nv = m + __logf(ssum);
      if (c + 1 < NCH && l < 16) bA[(c + 1) * 16 + l] = nv;
      v0 = __shfl(nv, g * 4 + 0); v1 = __shfl(nv, g * 4 + 1);
      v2 = __shfl(nv, g * 4 + 2); v3 = __shfl(nv, g * 4 + 3);
    }
  } else {
    const int i = l & 15;
    float w0 = 0.f, w1 = 0.f, w2 = 0.f, w3 = 0.f;
    if (l < 16) bB[(NCH - 1) * 16 + l] = 0.f;
    for (int c = NCH - 1; c >= 0; --c) {
      float4 mr = *reinterpret_cast<const float4*>(&Ms[c * 256 + i * 16 + g * 4]);
      float t0 = w0 + mr.x, t1 = w1 + mr.y, t2 = w2 + mr.z, t3 = w3 + mr.w;
      float m = fmaxf(fmaxf(t0, t1), fmaxf(t2, t3));
      float ssum = __expf(t0 - m) + __expf(t1 - m) + __expf(t2 - m) + __expf(t3 - m);
      lse_merge(m, ssum, __shfl_xor(m, 16), __shfl_xor(ssum, 16));
      lse_merge(m, ssum, __shfl_xor(m, 32), __shfl_xor(ssum, 32));
      float nw = m + __logf(ssum);
      if (c > 0 && l < 16) bB[(c - 1) * 16 + l] = nw;
      w0 = __shfl(nw, g * 4 + 0); w1 = __shfl(nw, g * 4 + 1);
      w2 = __shfl(nw, g * 4 + 2); w3 = __shfl(nw, g * 4 + 3);
    }
  }
}

// ---------------- Kernel 5: per-chunk replay, emit all alpha/beta rows ----------------
extern "C" __global__ void __launch_bounds__(64)
k_replay(float* __restrict__ out, const float* __restrict__ bA, const float* __restrict__ bB)
{
  const int l = threadIdx.x;
  const int g = l >> 4;
  const float* trs = out + OFF_TRS;
  const float* pis = out + OFF_PIS;
  if (blockIdx.x < NCH) {
    const int c = blockIdx.x;
    const int k0 = c * CLEN, k1 = min(k0 + CLEN, NK) - 1;
    const int j = l & 15;
    float v0 = bA[c * 16 + g * 4 + 0], v1 = bA[c * 16 + g * 4 + 1];
    float v2 = bA[c * 16 + g * 4 + 2], v3 = bA[c * 16 + g * 4 + 3];
    for (int k = k0; k <= k1; ++k) {
      const float* row = trs + (size_t)k * 256;
      float t0 = v0 + row[(g * 4 + 0) * 16 + j];
      float t1 = v1 + row[(g * 4 + 1) * 16 + j];
      float t2 = v2 + row[(g * 4 + 2) * 16 + j];
      float t3 = v3 + row[(g * 4 + 3) * 16 + j];
      float m = fmaxf(fmaxf(t0, t1), fmaxf(t2, t3));
      float ssum = __expf(t0 - m) + __expf(t1 - m) + __expf(t2 - m) + __expf(t3 - m);
      lse_merge(m, ssum, __shfl_xor(m, 16), __shfl_xor(ssum, 16));
      lse_merge(m, ssum, __shfl_xor(m, 32), __shfl_xor(ssum, 32));
      float nv = m + __logf(ssum) + pis[(size_t)(k + 1) * 16 + j];
      if (l < 16) out[OFF_ALPHA + (size_t)(k + 1) * 16 + l] = nv;
      v0 = __shfl(nv, g * 4 + 0); v1 = __shfl(nv, g * 4 + 1);
      v2 = __shfl(nv, g * 4 + 2); v3 = __shfl(nv, g * 4 + 3);
    }
  } else {
    const int c = blockIdx.x - NCH;
    const int k0 = c * CLEN, k1 = min(k0 + CLEN, NK) - 1;
    const int i = l & 15;
    float w0 = bB[c * 16 + g * 4 + 0], w1 = bB[c * 16 + g * 4 + 1];
    float w2 = bB[c * 16 + g * 4 + 2], w3 = bB[c * 16 + g * 4 + 3];
    for (int k = k1; k >= k0; --k) {
      float4 tr4 = *reinterpret_cast<const float4*>(&trs[(size_t)k * 256 + i * 16 + g * 4]);
      float4 pi4 = *reinterpret_cast<const float4*>(&pis[(size_t)(k + 1) * 16 + g * 4]);
      float t0 = w0 + tr4.x + pi4.x;
      float t1 = w1 + tr4.y + pi4.y;
      float t2 = w2 + tr4.z + pi4.z;
      float t3 = w3 + tr4.w + pi4.w;
      float m = fmaxf(fmaxf(t0, t1), fmaxf(t2, t3));
      float ssum = __expf(t0 - m) + __expf(t1 - m) + __expf(t2 - m) + __expf(t3 - m);
      lse_merge(m, ssum, __shfl_xor(m, 16), __shfl_xor(ssum, 16));
      lse_merge(m, ssum, __shfl_xor(m, 32), __shfl_xor(ssum, 32));
      float nw = m + __logf(ssum);
      if (l < 16) out[OFF_BETA + (size_t)k * 16 + l] = nw;
      w0 = __shfl(nw, g * 4 + 0); w1 = __shfl(nw, g * 4 + 1);
      w2 = __shfl(nw, g * 4 + 2); w3 = __shfl(nw, g * 4 + 3);
    }
  }
}

extern "C" void kernel_launch(void* const* d_in, const int* in_sizes, int n_in,
                              void* d_out, int out_size, void* d_ws, size_t ws_size,
                              hipStream_t stream)
{
  const float* s     = (const float*)d_in[0];
  const float* a_arr = (const float*)d_in[1];
  const float* pW1 = (const float*)d_in[2];
  const float* pb1 = (const float*)d_in[3];
  const float* pW2 = (const float*)d_in[4];
  const float* pb2 = (const float*)d_in[5];
  const float* pW3 = (const float*)d_in[6];
  const float* pb3 = (const float*)d_in[7];
  const float* oW1 = (const float*)d_in[8];
  const float* ob1 = (const float*)d_in[9];
  const float* oW2 = (const float*)d_in[10];
  const float* ob2 = (const float*)d_in[11];
  const float* oW3 = (const float*)d_in[12];
  const float* ob3 = (const float*)d_in[13];
  const float* a_log_std = (const float*)d_in[14];
  float* out = (float*)d_out;

  // ws float region: Ms[65536] | MsT[65536] | bA[4096] | bB[4096] | a0[16] | logtr0[16]
  float* wsf = (float*)d_ws;
  float* Ms  = wsf;
  float* MsT = wsf + 65536;
  float* bA  = wsf + 131072;
  float* bB  = wsf + 135168;
  float* a0  = wsf + 139264;
  float* lt0 = wsf + 139280;
  unsigned short* wbase = (unsigned short*)((char*)d_ws + WS_WEIGHT_OFF);

  k_wconv<<<(W_TOTAL + 255) / 256, 256, 0, stream>>>(pW1, pW2, pW3, oW1, oW2, oW3, wbase);
  k_mlp<<<TT / 64, 256, 0, stream>>>(s, a_arr, pb1, pb2, pb3, ob1, ob2, ob3,
                                     a_log_std, wbase, out, lt0);
  k_softmax<<<(NK * 16 + 255) / 256, 256, 0, stream>>>(out, lt0, a0);
  k_chunk<<<NCH, 256, 0, stream>>>(out, Ms, MsT);
  k_boundary<<<2, 64, 0, stream>>>(Ms, MsT, a0, bA, bB);
  k_replay<<<2 * NCH, 64, 0, stream>>>(out, bA, bB);
}

// Round 4
// 753.125 us; speedup vs baseline: 1.7016x; 1.4440x over previous
//
#include <hip/hip_runtime.h>
#include <cstddef>

// Problem dims
#define TT 65536
#define NK (TT - 1)      // scan steps
#define NCH 256          // chunks
#define CLEN 256         // chunk length

// d_out offsets (floats): log_alpha, log_beta, log_trs, log_pis, entropy
#define OFF_ALPHA 0
#define OFF_BETA  (TT * 16)
#define OFF_TRS   (2 * TT * 16)
#define OFF_PIS   (OFF_TRS + NK * 256)
#define OFF_ENT   (OFF_PIS + TT * 16)

// bf16 weight plane element offsets (ushort units), layout [n][k], hi plane only
#define W_PW1 0        // 256 x 64
#define W_PW2 16384    // 256 x 256
#define W_PW3 81920    // 128 x 256
#define W_OW1 114688   // 256 x 64
#define W_OW2 131072   // 256 x 256
#define W_OW3 196608   // 272 x 256
#define W_TOTAL 266240
#define WS_WEIGHT_OFF 557184   // bytes: scan float region sits below this

typedef __attribute__((ext_vector_type(8))) short bf16x8;
typedef __attribute__((ext_vector_type(4))) float f32x4;
typedef __attribute__((ext_vector_type(4))) unsigned short us4;

__device__ __forceinline__ unsigned short bf16_rne(float x) {
  unsigned int u = __float_as_uint(x);
  unsigned int r = u + 0x7FFFu + ((u >> 16) & 1u);
  return (unsigned short)(r >> 16);
}

__device__ __forceinline__ void lse_merge(float& m, float& s, float mo, float so) {
  float mm = fmaxf(m, mo);
  s = s * __expf(m - mm) + so * __expf(mo - mm);
  m = mm;
}

// ---------------- Kernel 0: weight convert fp32 -> bf16 hi plane, [n][k] ----------------
extern "C" __global__ void __launch_bounds__(256)
k_wconv(const float* __restrict__ pW1, const float* __restrict__ pW2,
        const float* __restrict__ pW3, const float* __restrict__ oW1,
        const float* __restrict__ oW2, const float* __restrict__ oW3,
        unsigned short* __restrict__ wbase)
{
  int e = blockIdx.x * 256 + threadIdx.x;
  if (e >= W_TOTAL) return;
  float x;
  if (e < W_PW2)      { int l = e - W_PW1; int n = l >> 6; int k = l & 63;  x = pW1[k * 256 + n]; }
  else if (e < W_PW3) { int l = e - W_PW2; int n = l >> 8; int k = l & 255; x = pW2[k * 256 + n]; }
  else if (e < W_OW1) { int l = e - W_PW3; int n = l >> 8; int k = l & 255; x = pW3[k * 128 + n]; }
  else if (e < W_OW2) { int l = e - W_OW1; int n = l >> 6; int k = l & 63;  x = oW1[k * 256 + n]; }
  else if (e < W_OW3) { int l = e - W_OW2; int n = l >> 8; int k = l & 255; x = oW2[k * 256 + n]; }
  else                { int l = e - W_OW3; int n = l >> 8; int k = l & 255; x = oW3[k * 272 + n]; }
  wbase[e] = bf16_rne(x);
}

// ---------------- Kernel 1: fused MLPs, pure bf16 MFMA, 32 samples/wave ----------------
// H^T = W^T * X^T per 16x16x32 tile. A-frag = W[n][k], B-frag = X[sample][k].
// D: sample = lane&15, n = nt*16 + (lane>>4)*4 + reg. Wave w owns samples w*32..w*32+31
// (two B-frag sets A/B -> 2 MFMAs per weight fragment load).

template<int K, int NT>
__device__ __forceinline__ void gemm2(const unsigned short* __restrict__ Wh,
                                      const unsigned short* Xh,
                                      int sA, int sB, int l15, int kb,
                                      f32x4* accA, f32x4* accB)
{
  #pragma unroll
  for (int nt = 0; nt < NT; ++nt) {
    accA[nt] = (f32x4){0.f, 0.f, 0.f, 0.f};
    accB[nt] = (f32x4){0.f, 0.f, 0.f, 0.f};
  }
  const int sw = (sA & 7) << 3;   // sB = sA+16 -> same swizzle
  #pragma unroll
  for (int ks = 0; ks < K / 32; ++ks) {
    const int kk = ks * 32 + kb * 8;
    bf16x8 xa = *(const bf16x8*)&Xh[sA * K + (kk ^ sw)];
    bf16x8 xb = *(const bf16x8*)&Xh[sB * K + (kk ^ sw)];
    #pragma unroll
    for (int nt = 0; nt < NT; ++nt) {
      bf16x8 wh = *(const bf16x8*)&Wh[(nt * 16 + l15) * K + kk];
      accA[nt] = __builtin_amdgcn_mfma_f32_16x16x32_bf16(wh, xa, accA[nt], 0, 0, 0);
      accB[nt] = __builtin_amdgcn_mfma_f32_16x16x32_bf16(wh, xb, accB[nt], 0, 0, 0);
    }
  }
}

template<int NT>
__device__ __forceinline__ void relu_store2(const f32x4* accA, const f32x4* accB,
                                            const float* __restrict__ bias,
                                            unsigned short* Xh, int sA, int sB, int kb)
{
  const int sw = (sA & 7) << 3;
  #pragma unroll
  for (int nt = 0; nt < NT; ++nt) {
    const int n0 = nt * 16 + kb * 4;
    float4 b4 = *(const float4*)&bias[n0];
    us4 va, vb;
    #pragma unroll
    for (int r = 0; r < 4; ++r) {
      va[r] = bf16_rne(fmaxf(accA[nt][r] + (&b4.x)[r], 0.f));
      vb[r] = bf16_rne(fmaxf(accB[nt][r] + (&b4.x)[r], 0.f));
    }
    *(us4*)&Xh[sA * 256 + (n0 ^ sw)] = va;
    *(us4*)&Xh[sB * 256 + (n0 ^ sw)] = vb;
  }
}

extern "C" __global__ void __launch_bounds__(256, 2)
k_mlp(const float* __restrict__ s, const float* __restrict__ a_arr,
      const float* __restrict__ pb1, const float* __restrict__ pb2,
      const float* __restrict__ pb3, const float* __restrict__ ob1,
      const float* __restrict__ ob2, const float* __restrict__ ob3,
      const float* __restrict__ a_log_std,
      const unsigned short* __restrict__ wbase,
      float* __restrict__ out, float* __restrict__ ws_logtr0)
{
  __shared__ __align__(16) unsigned short ShS[128 * 64];    // 16 KB
  __shared__ __align__(16) unsigned short XhS[128 * 256];   // 64 KB

  const int tid = threadIdx.x;
  const int r0 = blockIdx.x * 128;
  const int w = tid >> 6, lane = tid & 63;
  const int l15 = lane & 15, kb = lane >> 4;
  const int sA = w * 32 + l15, sB = sA + 16;
  const int tA = r0 + sA, tB = r0 + sB;

  // ---- stage s -> ShS (bf16 hi, XOR-swizzled rows) ----
  #pragma unroll
  for (int q = 0; q < 8; ++q) {
    int f4 = q * 256 + tid;
    int e = f4 * 4;
    int row = e >> 6, col = e & 63;
    float4 v = *(const float4*)&s[(size_t)(r0 + row) * 64 + col];
    us4 vh;
    #pragma unroll
    for (int r = 0; r < 4; ++r) vh[r] = bf16_rne((&v.x)[r]);
    int cs = col ^ ((row & 7) << 3);
    *(us4*)&ShS[row * 64 + cs] = vh;
  }
  __syncthreads();

  f32x4 accA[17], accB[17];

  // ---- policy MLP ----
  gemm2<64, 16>(wbase + W_PW1, ShS, sA, sB, l15, kb, accA, accB);
  relu_store2<16>(accA, accB, pb1, XhS, sA, sB, kb);
  __syncthreads();
  gemm2<256, 16>(wbase + W_PW2, XhS, sA, sB, l15, kb, accA, accB);
  relu_store2<16>(accA, accB, pb2, XhS, sA, sB, kb);
  __syncthreads();
  gemm2<256, 8>(wbase + W_PW3, XhS, sA, sB, l15, kb, accA, accB);

  // ---- mean -> log_pis (both sample sets) ----
  {
    const int a0i = (kb & 1) * 4;
    float ist[4], ct[4];
    #pragma unroll
    for (int r = 0; r < 4; ++r) {
      float th = tanhf(a_log_std[a0i + r]);
      float logstd = -5.0f + 3.5f * (th + 1.0f);
      ist[r] = __expf(-logstd);
      ct[r] = -logstd - 0.91893853320467274f;  // -logstd - 0.5*log(2pi)
    }
    float4 avA = *(const float4*)&a_arr[(size_t)tA * 8 + a0i];
    float4 avB = *(const float4*)&a_arr[(size_t)tB * 8 + a0i];
    #pragma unroll
    for (int nt = 0; nt < 8; ++nt) {
      float4 b4 = *(const float4*)&pb3[nt * 16 + kb * 4];
      float s4A = 0.f, s4B = 0.f;
      #pragma unroll
      for (int r = 0; r < 4; ++r) {
        float mA = fminf(fmaxf(accA[nt][r] + (&b4.x)[r], -10.f), 10.f);
        float mB = fminf(fmaxf(accB[nt][r] + (&b4.x)[r], -10.f), 10.f);
        float zA = ((&avA.x)[r] - mA) * ist[r];
        float zB = ((&avB.x)[r] - mB) * ist[r];
        s4A += fmaf(-0.5f * zA, zA, ct[r]);
        s4B += fmaf(-0.5f * zB, zB, ct[r]);
      }
      s4A += __shfl_xor(s4A, 16);
      s4B += __shfl_xor(s4B, 16);
      if (!(kb & 1)) {
        out[OFF_PIS + (size_t)tA * 16 + nt * 2 + (kb >> 1)] = s4A;
        out[OFF_PIS + (size_t)tB * 16 + nt * 2 + (kb >> 1)] = s4B;
      }
    }
  }
  __syncthreads();

  // ---- option MLP ----
  gemm2<64, 16>(wbase + W_OW1, ShS, sA, sB, l15, kb, accA, accB);
  relu_store2<16>(accA, accB, ob1, XhS, sA, sB, kb);
  __syncthreads();
  gemm2<256, 16>(wbase + W_OW2, XhS, sA, sB, l15, kb, accA, accB);
  relu_store2<16>(accA, accB, ob2, XhS, sA, sB, kb);
  __syncthreads();
  gemm2<256, 17>(wbase + W_OW3, XhS, sA, sB, l15, kb, accA, accB);

  // ---- raw logits cols 0..255 -> log_trs slot (t >= 1) ----
  #pragma unroll
  for (int nt = 0; nt < 16; ++nt) {
    const int n0 = nt * 16 + kb * 4;
    float4 b4 = *(const float4*)&ob3[n0];
    float4 vA, vB;
    #pragma unroll
    for (int r = 0; r < 4; ++r) {
      (&vA.x)[r] = accA[nt][r] + (&b4.x)[r];
      (&vB.x)[r] = accB[nt][r] + (&b4.x)[r];
    }
    if (tA >= 1) *(float4*)&out[OFF_TRS + (size_t)(tA - 1) * 256 + n0] = vA;
    *(float4*)&out[OFF_TRS + (size_t)(tB - 1) * 256 + n0] = vB;  // tB >= 16 always
  }
  // ---- t=0 cols 256..271 -> ws_logtr0 ----
  if (tA == 0) {
    const int n0 = 256 + kb * 4;
    float4 b4 = *(const float4*)&ob3[n0];
    float4 v;
    #pragma unroll
    for (int r = 0; r < 4; ++r) (&v.x)[r] = accA[16][r] + (&b4.x)[r];
    *(float4*)&ws_logtr0[kb * 4] = v;
  }
}

// ---------------- Kernel 2: fused log_softmax + entropy + chunk fold ----------------
// Per k: row-softmax raw logits (in-register, 16-lane shfl groups), write normalized
// trs + entropy, then fold G = g + log_pi into the chunk matrix (1 barrier/iter via
// double-buffered LDS).
extern "C" __global__ void __launch_bounds__(256)
k_chunk(float* __restrict__ out, float* __restrict__ Ms, float* __restrict__ MsT)
{
  __shared__ float Msh[2][256];
  __shared__ float Gsh[2][256];
  const int c = blockIdx.x, tid = threadIdx.x;
  const int i = tid >> 4, j = tid & 15;
  const int k0 = c * CLEN;
  const int k1 = min(k0 + CLEN, NK) - 1;
  float* trs = out + OFF_TRS;
  const float* pis = out + OFF_PIS;

  float mij = 0.f;
  float raw = trs[(size_t)k0 * 256 + tid];
  float pn  = pis[(size_t)(k0 + 1) * 16 + j];
  for (int k = k0; k <= k1; ++k) {
    float rawn = 0.f, pnn = 0.f;
    if (k < k1) {   // 1-deep prefetch
      rawn = trs[(size_t)(k + 1) * 256 + tid];
      pnn  = pis[(size_t)(k + 2) * 16 + j];
    }
    // row softmax over j (16-lane group)
    float mx = raw;
    #pragma unroll
    for (int d = 1; d < 16; d <<= 1) mx = fmaxf(mx, __shfl_xor(mx, d));
    float ex = __expf(raw - mx);
    float sm = ex;
    #pragma unroll
    for (int d = 1; d < 16; d <<= 1) sm += __shfl_xor(sm, d);
    float inv = 1.0f / sm;
    float ls = mx + __logf(sm);
    float g = raw - ls;
    trs[(size_t)k * 256 + tid] = g;
    float h = g * ex * inv;   // g * exp(g)
    float hs = h;
    #pragma unroll
    for (int d = 1; d < 16; d <<= 1) hs += __shfl_xor(hs, d);
    if (j == 0) out[OFF_ENT + (size_t)k * 16 + i] = -hs;

    float G = g + pn;
    if (k == k0) {
      mij = G;
    } else {
      const int sel = (k - k0) & 1;
      Msh[sel][tid] = mij;
      Gsh[sel][tid] = G;
      __syncthreads();
      float tq[16];
      #pragma unroll
      for (int q = 0; q < 16; ++q) tq[q] = Msh[sel][i * 16 + q] + Gsh[sel][q * 16 + j];
      float mx2 = tq[0];
      #pragma unroll
      for (int q = 1; q < 16; ++q) mx2 = fmaxf(mx2, tq[q]);
      float ssum = 0.f;
      #pragma unroll
      for (int q = 0; q < 16; ++q) ssum += __expf(tq[q] - mx2);
      mij = mx2 + __logf(ssum);
    }
    raw = rawn; pn = pnn;
  }
  Ms[c * 256 + tid] = mij;
  MsT[c * 256 + j * 16 + i] = mij;  // transposed copy for the alpha direction
}

// ---------------- Kernel 3: boundary scan (1 wave per direction) + a0 setup ----------------
extern "C" __global__ void __launch_bounds__(64)
k_boundary(const float* __restrict__ Ms, const float* __restrict__ MsT,
           const float* __restrict__ lt0, float* __restrict__ out,
           float* __restrict__ bA, float* __restrict__ bB)
{
  const int l = threadIdx.x;
  const int g = l >> 4;
  const int j = l & 15;
  if (blockIdx.x == 0) {
    // a0 = log_softmax(lt0) + log_pis[0]; lane l holds a0[p] for p = l&15
    float ltp = lt0[j];
    float mx = ltp;
    #pragma unroll
    for (int d = 1; d < 16; d <<= 1) mx = fmaxf(mx, __shfl_xor(mx, d));
    float sm = __expf(ltp - mx);
    #pragma unroll
    for (int d = 1; d < 16; d <<= 1) sm += __shfl_xor(sm, d);
    float ls = mx + __logf(sm);
    float a0p = ltp - ls + out[OFF_PIS + j];
    if (l < 16) { bA[l] = a0p; out[OFF_ALPHA + l] = a0p; }
    float v0 = __shfl(a0p, g * 4 + 0), v1 = __shfl(a0p, g * 4 + 1);
    float v2 = __shfl(a0p, g * 4 + 2), v3 = __shfl(a0p, g * 4 + 3);
    for (int c = 0; c < NCH; ++c) {
      float4 mr = *reinterpret_cast<const float4*>(&MsT[c * 256 + j * 16 + g * 4]);
      float t0 = v0 + mr.x, t1 = v1 + mr.y, t2 = v2 + mr.z, t3 = v3 + mr.w;
      float m = fmaxf(fmaxf(t0, t1), fmaxf(t2, t3));
      float ssum = __expf(t0 - m) + __expf(t1 - m) + __expf(t2 - m) + __expf(t3 - m);
      lse_merge(m, ssum, __shfl_xor(m, 16), __shfl_xor(ssum, 16));
      lse_merge(m, ssum, __shfl_xor(m, 32), __shfl_xor(ssum, 32));
      float nv = m + __logf(ssum);
      if (c + 1 < NCH && l < 16) bA[(c + 1) * 16 + l] = nv;
      v0 = __shfl(nv, g * 4 + 0); v1 = __shfl(nv, g * 4 + 1);
      v2 = __shfl(nv, g * 4 + 2); v3 = __shfl(nv, g * 4 + 3);
    }
  } else {
    const int i = j;
    float w0 = 0.f, w1 = 0.f, w2 = 0.f, w3 = 0.f;
    if (l < 16) {
      bB[(NCH - 1) * 16 + l] = 0.f;
      out[OFF_BETA + (size_t)(TT - 1) * 16 + l] = 0.f;
    }
    for (int c = NCH - 1; c >= 0; --c) {
      float4 mr = *reinterpret_cast<const float4*>(&Ms[c * 256 + i * 16 + g * 4]);
      float t0 = w0 + mr.x, t1 = w1 + mr.y, t2 = w2 + mr.z, t3 = w3 + mr.w;
      float m = fmaxf(fmaxf(t0, t1), fmaxf(t2, t3));
      float ssum = __expf(t0 - m) + __expf(t1 - m) + __expf(t2 - m) + __expf(t3 - m);
      lse_merge(m, ssum, __shfl_xor(m, 16), __shfl_xor(ssum, 16));
      lse_merge(m, ssum, __shfl_xor(m, 32), __shfl_xor(ssum, 32));
      float nw = m + __logf(ssum);
      if (c > 0 && l < 16) bB[(c - 1) * 16 + l] = nw;
      w0 = __shfl(nw, g * 4 + 0); w1 = __shfl(nw, g * 4 + 1);
      w2 = __shfl(nw, g * 4 + 2); w3 = __shfl(nw, g * 4 + 3);
    }
  }
}

// ---------------- Kernel 4: per-chunk replay with 1-deep prefetch ----------------
extern "C" __global__ void __launch_bounds__(64)
k_replay(float* __restrict__ out, const float* __restrict__ bA, const float* __restrict__ bB)
{
  const int l = threadIdx.x;
  const int g = l >> 4;
  const float* trs = out + OFF_TRS;
  const float* pis = out + OFF_PIS;
  if (blockIdx.x < NCH) {
    const int c = blockIdx.x;
    const int k0 = c * CLEN, k1 = min(k0 + CLEN, NK) - 1;
    const int j = l & 15;
    float v0 = bA[c * 16 + g * 4 + 0], v1 = bA[c * 16 + g * 4 + 1];
    float v2 = bA[c * 16 + g * 4 + 2], v3 = bA[c * 16 + g * 4 + 3];
    const float* row = trs + (size_t)k0 * 256;
    float r0_ = row[(g * 4 + 0) * 16 + j], r1_ = row[(g * 4 + 1) * 16 + j];
    float r2_ = row[(g * 4 + 2) * 16 + j], r3_ = row[(g * 4 + 3) * 16 + j];
    float p_ = pis[(size_t)(k0 + 1) * 16 + j];
    for (int k = k0; k <= k1; ++k) {
      float n0 = 0.f, n1 = 0.f, n2 = 0.f, n3 = 0.f, np = 0.f;
      if (k < k1) {
        const float* rw = trs + (size_t)(k + 1) * 256;
        n0 = rw[(g * 4 + 0) * 16 + j]; n1 = rw[(g * 4 + 1) * 16 + j];
        n2 = rw[(g * 4 + 2) * 16 + j]; n3 = rw[(g * 4 + 3) * 16 + j];
        np = pis[(size_t)(k + 2) * 16 + j];
      }
      float t0 = v0 + r0_, t1 = v1 + r1_, t2 = v2 + r2_, t3 = v3 + r3_;
      float m = fmaxf(fmaxf(t0, t1), fmaxf(t2, t3));
      float ssum = __expf(t0 - m) + __expf(t1 - m) + __expf(t2 - m) + __expf(t3 - m);
      lse_merge(m, ssum, __shfl_xor(m, 16), __shfl_xor(ssum, 16));
      lse_merge(m, ssum, __shfl_xor(m, 32), __shfl_xor(ssum, 32));
      float nv = m + __logf(ssum) + p_;
      if (l < 16) out[OFF_ALPHA + (size_t)(k + 1) * 16 + l] = nv;
      v0 = __shfl(nv, g * 4 + 0); v1 = __shfl(nv, g * 4 + 1);
      v2 = __shfl(nv, g * 4 + 2); v3 = __shfl(nv, g * 4 + 3);
      r0_ = n0; r1_ = n1; r2_ = n2; r3_ = n3; p_ = np;
    }
  } else {
    const int c = blockIdx.x - NCH;
    const int k0 = c * CLEN, k1 = min(k0 + CLEN, NK) - 1;
    const int i = l & 15;
    float w0 = bB[c * 16 + g * 4 + 0], w1 = bB[c * 16 + g * 4 + 1];
    float w2 = bB[c * 16 + g * 4 + 2], w3 = bB[c * 16 + g * 4 + 3];
    float4 tr_ = *reinterpret_cast<const float4*>(&trs[(size_t)k1 * 256 + i * 16 + g * 4]);
    float4 pi_ = *reinterpret_cast<const float4*>(&pis[(size_t)(k1 + 1) * 16 + g * 4]);
    for (int k = k1; k >= k0; --k) {
      float4 trn = make_float4(0.f, 0.f, 0.f, 0.f), pin = trn;
      if (k > k0) {
        trn = *reinterpret_cast<const float4*>(&trs[(size_t)(k - 1) * 256 + i * 16 + g * 4]);
        pin = *reinterpret_cast<const float4*>(&pis[(size_t)k * 16 + g * 4]);
      }
      float t0 = w0 + tr_.x + pi_.x;
      float t1 = w1 + tr_.y + pi_.y;
      float t2 = w2 + tr_.z + pi_.z;
      float t3 = w3 + tr_.w + pi_.w;
      float m = fmaxf(fmaxf(t0, t1), fmaxf(t2, t3));
      float ssum = __expf(t0 - m) + __expf(t1 - m) + __expf(t2 - m) + __expf(t3 - m);
      lse_merge(m, ssum, __shfl_xor(m, 16), __shfl_xor(ssum, 16));
      lse_merge(m, ssum, __shfl_xor(m, 32), __shfl_xor(ssum, 32));
      float nw = m + __logf(ssum);
      if (l < 16) out[OFF_BETA + (size_t)k * 16 + l] = nw;
      w0 = __shfl(nw, g * 4 + 0); w1 = __shfl(nw, g * 4 + 1);
      w2 = __shfl(nw, g * 4 + 2); w3 = __shfl(nw, g * 4 + 3);
      tr_ = trn; pi_ = pin;
    }
  }
}

extern "C" void kernel_launch(void* const* d_in, const int* in_sizes, int n_in,
                              void* d_out, int out_size, void* d_ws, size_t ws_size,
                              hipStream_t stream)
{
  const float* s     = (const float*)d_in[0];
  const float* a_arr = (const float*)d_in[1];
  const float* pW1 = (const float*)d_in[2];
  const float* pb1 = (const float*)d_in[3];
  const float* pW2 = (const float*)d_in[4];
  const float* pb2 = (const float*)d_in[5];
  const float* pW3 = (const float*)d_in[6];
  const float* pb3 = (const float*)d_in[7];
  const float* oW1 = (const float*)d_in[8];
  const float* ob1 = (const float*)d_in[9];
  const float* oW2 = (const float*)d_in[10];
  const float* ob2 = (const float*)d_in[11];
  const float* oW3 = (const float*)d_in[12];
  const float* ob3 = (const float*)d_in[13];
  const float* a_log_std = (const float*)d_in[14];
  float* out = (float*)d_out;

  // ws float region: Ms[65536] | MsT[65536] | bA[4096] | bB[4096] | (gap) | logtr0[16]
  float* wsf = (float*)d_ws;
  float* Ms  = wsf;
  float* MsT = wsf + 65536;
  float* bA  = wsf + 131072;
  float* bB  = wsf + 135168;
  float* lt0 = wsf + 139280;
  unsigned short* wbase = (unsigned short*)((char*)d_ws + WS_WEIGHT_OFF);

  k_wconv<<<(W_TOTAL + 255) / 256, 256, 0, stream>>>(pW1, pW2, pW3, oW1, oW2, oW3, wbase);
  k_mlp<<<TT / 128, 256, 0, stream>>>(s, a_arr, pb1, pb2, pb3, ob1, ob2, ob3,
                                      a_log_std, wbase, out, lt0);
  k_chunk<<<NCH, 256, 0, stream>>>(out, Ms, MsT);
  k_boundary<<<2, 64, 0, stream>>>(Ms, MsT, lt0, out, bA, bB);
  k_replay<<<2 * NCH, 64, 0, stream>>>(out, bA, bB);
}

// Round 5
// 505.248 us; speedup vs baseline: 2.5365x; 1.4906x over previous
//
#include <hip/hip_runtime.h>
#include <cstddef>

// Problem dims
#define TT 65536
#define NK (TT - 1)      // scan steps
#define NCH 256          // chunks
#define CLEN 256         // chunk length

// d_out offsets (floats): log_alpha, log_beta, log_trs, log_pis, entropy
#define OFF_ALPHA 0
#define OFF_BETA  (TT * 16)
#define OFF_TRS   (2 * TT * 16)
#define OFF_PIS   (OFF_TRS + NK * 256)
#define OFF_ENT   (OFF_PIS + TT * 16)

// bf16 weight plane element offsets (ushort units), layout [n][k], hi plane only
#define W_PW1 0        // 256 x 64
#define W_PW2 16384    // 256 x 256
#define W_PW3 81920    // 128 x 256
#define W_OW1 114688   // 256 x 64
#define W_OW2 131072   // 256 x 256
#define W_OW3 196608   // 272 x 256
#define W_TOTAL 266240
#define WS_WEIGHT_OFF 557184   // bytes: scan float region sits below this

typedef __attribute__((ext_vector_type(8))) short bf16x8;
typedef __attribute__((ext_vector_type(4))) float f32x4;
typedef __attribute__((ext_vector_type(4))) unsigned short us4;

__device__ __forceinline__ unsigned short bf16_rne(float x) {
  unsigned int u = __float_as_uint(x);
  unsigned int r = u + 0x7FFFu + ((u >> 16) & 1u);
  return (unsigned short)(r >> 16);
}

__device__ __forceinline__ void lse_merge(float& m, float& s, float mo, float so) {
  float mm = fmaxf(m, mo);
  s = s * __expf(m - mm) + so * __expf(mo - mm);
  m = mm;
}

// ---------------- Kernel 0: weight convert fp32 -> bf16 hi plane, [n][k] ----------------
extern "C" __global__ void __launch_bounds__(256)
k_wconv(const float* __restrict__ pW1, const float* __restrict__ pW2,
        const float* __restrict__ pW3, const float* __restrict__ oW1,
        const float* __restrict__ oW2, const float* __restrict__ oW3,
        unsigned short* __restrict__ wbase)
{
  int e = blockIdx.x * 256 + threadIdx.x;
  if (e >= W_TOTAL) return;
  float x;
  if (e < W_PW2)      { int l = e - W_PW1; int n = l >> 6; int k = l & 63;  x = pW1[k * 256 + n]; }
  else if (e < W_PW3) { int l = e - W_PW2; int n = l >> 8; int k = l & 255; x = pW2[k * 256 + n]; }
  else if (e < W_OW1) { int l = e - W_PW3; int n = l >> 8; int k = l & 255; x = pW3[k * 128 + n]; }
  else if (e < W_OW2) { int l = e - W_OW1; int n = l >> 6; int k = l & 63;  x = oW1[k * 256 + n]; }
  else if (e < W_OW3) { int l = e - W_OW2; int n = l >> 8; int k = l & 255; x = oW2[k * 256 + n]; }
  else                { int l = e - W_OW3; int n = l >> 8; int k = l & 255; x = oW3[k * 272 + n]; }
  wbase[e] = bf16_rne(x);
}

// ---------------- Kernel 1: fused MLPs, pure bf16 MFMA, 32 samples/wave ----------------
// H^T = W^T * X^T per 16x16x32 tile. A-frag = W[n][k], B-frag = X[sample][k].
// D: sample = lane&15, n = nt*16 + (lane>>4)*4 + reg. Wave w owns samples w*32..w*32+31.
// Epilogue now also does the row log_softmax + entropy (fused, in-register).

template<int K, int NT>
__device__ __forceinline__ void gemm2(const unsigned short* __restrict__ Wh,
                                      const unsigned short* Xh,
                                      int sA, int sB, int l15, int kb,
                                      f32x4* accA, f32x4* accB)
{
  #pragma unroll
  for (int nt = 0; nt < NT; ++nt) {
    accA[nt] = (f32x4){0.f, 0.f, 0.f, 0.f};
    accB[nt] = (f32x4){0.f, 0.f, 0.f, 0.f};
  }
  const int sw = (sA & 7) << 3;   // sB = sA+16 -> same swizzle
  #pragma unroll
  for (int ks = 0; ks < K / 32; ++ks) {
    const int kk = ks * 32 + kb * 8;
    bf16x8 xa = *(const bf16x8*)&Xh[sA * K + (kk ^ sw)];
    bf16x8 xb = *(const bf16x8*)&Xh[sB * K + (kk ^ sw)];
    #pragma unroll
    for (int nt = 0; nt < NT; ++nt) {
      bf16x8 wh = *(const bf16x8*)&Wh[(nt * 16 + l15) * K + kk];
      accA[nt] = __builtin_amdgcn_mfma_f32_16x16x32_bf16(wh, xa, accA[nt], 0, 0, 0);
      accB[nt] = __builtin_amdgcn_mfma_f32_16x16x32_bf16(wh, xb, accB[nt], 0, 0, 0);
    }
  }
}

template<int NT>
__device__ __forceinline__ void relu_store2(const f32x4* accA, const f32x4* accB,
                                            const float* __restrict__ bias,
                                            unsigned short* Xh, int sA, int sB, int kb)
{
  const int sw = (sA & 7) << 3;
  #pragma unroll
  for (int nt = 0; nt < NT; ++nt) {
    const int n0 = nt * 16 + kb * 4;
    float4 b4 = *(const float4*)&bias[n0];
    us4 va, vb;
    #pragma unroll
    for (int r = 0; r < 4; ++r) {
      va[r] = bf16_rne(fmaxf(accA[nt][r] + (&b4.x)[r], 0.f));
      vb[r] = bf16_rne(fmaxf(accB[nt][r] + (&b4.x)[r], 0.f));
    }
    *(us4*)&Xh[sA * 256 + (n0 ^ sw)] = va;
    *(us4*)&Xh[sB * 256 + (n0 ^ sw)] = vb;
  }
}

extern "C" __global__ void __launch_bounds__(256, 2)
k_mlp(const float* __restrict__ s, const float* __restrict__ a_arr,
      const float* __restrict__ pb1, const float* __restrict__ pb2,
      const float* __restrict__ pb3, const float* __restrict__ ob1,
      const float* __restrict__ ob2, const float* __restrict__ ob3,
      const float* __restrict__ a_log_std,
      const unsigned short* __restrict__ wbase,
      float* __restrict__ out, float* __restrict__ ws_logtr0)
{
  __shared__ __align__(16) unsigned short ShS[128 * 64];    // 16 KB
  __shared__ __align__(16) unsigned short XhS[128 * 256];   // 64 KB

  const int tid = threadIdx.x;
  const int r0 = blockIdx.x * 128;
  const int w = tid >> 6, lane = tid & 63;
  const int l15 = lane & 15, kb = lane >> 4;
  const int sA = w * 32 + l15, sB = sA + 16;
  const int tA = r0 + sA, tB = r0 + sB;

  // ---- stage s -> ShS (bf16 hi, XOR-swizzled rows) ----
  #pragma unroll
  for (int q = 0; q < 8; ++q) {
    int f4 = q * 256 + tid;
    int e = f4 * 4;
    int row = e >> 6, col = e & 63;
    float4 v = *(const float4*)&s[(size_t)(r0 + row) * 64 + col];
    us4 vh;
    #pragma unroll
    for (int r = 0; r < 4; ++r) vh[r] = bf16_rne((&v.x)[r]);
    int cs = col ^ ((row & 7) << 3);
    *(us4*)&ShS[row * 64 + cs] = vh;
  }
  __syncthreads();

  f32x4 accA[17], accB[17];

  // ---- policy MLP ----
  gemm2<64, 16>(wbase + W_PW1, ShS, sA, sB, l15, kb, accA, accB);
  relu_store2<16>(accA, accB, pb1, XhS, sA, sB, kb);
  __syncthreads();
  gemm2<256, 16>(wbase + W_PW2, XhS, sA, sB, l15, kb, accA, accB);
  relu_store2<16>(accA, accB, pb2, XhS, sA, sB, kb);
  __syncthreads();
  gemm2<256, 8>(wbase + W_PW3, XhS, sA, sB, l15, kb, accA, accB);

  // ---- mean -> log_pis (both sample sets) ----
  {
    const int a0i = (kb & 1) * 4;
    float ist[4], ct[4];
    #pragma unroll
    for (int r = 0; r < 4; ++r) {
      float th = tanhf(a_log_std[a0i + r]);
      float logstd = -5.0f + 3.5f * (th + 1.0f);
      ist[r] = __expf(-logstd);
      ct[r] = -logstd - 0.91893853320467274f;  // -logstd - 0.5*log(2pi)
    }
    float4 avA = *(const float4*)&a_arr[(size_t)tA * 8 + a0i];
    float4 avB = *(const float4*)&a_arr[(size_t)tB * 8 + a0i];
    #pragma unroll
    for (int nt = 0; nt < 8; ++nt) {
      float4 b4 = *(const float4*)&pb3[nt * 16 + kb * 4];
      float s4A = 0.f, s4B = 0.f;
      #pragma unroll
      for (int r = 0; r < 4; ++r) {
        float mA = fminf(fmaxf(accA[nt][r] + (&b4.x)[r], -10.f), 10.f);
        float mB = fminf(fmaxf(accB[nt][r] + (&b4.x)[r], -10.f), 10.f);
        float zA = ((&avA.x)[r] - mA) * ist[r];
        float zB = ((&avB.x)[r] - mB) * ist[r];
        s4A += fmaf(-0.5f * zA, zA, ct[r]);
        s4B += fmaf(-0.5f * zB, zB, ct[r]);
      }
      s4A += __shfl_xor(s4A, 16);
      s4B += __shfl_xor(s4B, 16);
      if (!(kb & 1)) {
        out[OFF_PIS + (size_t)tA * 16 + nt * 2 + (kb >> 1)] = s4A;
        out[OFF_PIS + (size_t)tB * 16 + nt * 2 + (kb >> 1)] = s4B;
      }
    }
  }
  __syncthreads();

  // ---- option MLP ----
  gemm2<64, 16>(wbase + W_OW1, ShS, sA, sB, l15, kb, accA, accB);
  relu_store2<16>(accA, accB, ob1, XhS, sA, sB, kb);
  __syncthreads();
  gemm2<256, 16>(wbase + W_OW2, XhS, sA, sB, l15, kb, accA, accB);
  relu_store2<16>(accA, accB, ob2, XhS, sA, sB, kb);
  __syncthreads();
  gemm2<256, 17>(wbase + W_OW3, XhS, sA, sB, l15, kb, accA, accB);

  // ---- fused row log_softmax + entropy -> log_trs / entropy (t >= 1) ----
  // Row i=nt of the 16x16 logits: cols j = kb*4 + r across the 4 kb-lane-groups.
  #pragma unroll
  for (int nt = 0; nt < 16; ++nt) {
    const int n0 = nt * 16 + kb * 4;
    float4 b4 = *(const float4*)&ob3[n0];
    float vA0 = accA[nt][0] + b4.x, vA1 = accA[nt][1] + b4.y;
    float vA2 = accA[nt][2] + b4.z, vA3 = accA[nt][3] + b4.w;
    float vB0 = accB[nt][0] + b4.x, vB1 = accB[nt][1] + b4.y;
    float vB2 = accB[nt][2] + b4.z, vB3 = accB[nt][3] + b4.w;
    float mxA = fmaxf(fmaxf(vA0, vA1), fmaxf(vA2, vA3));
    float mxB = fmaxf(fmaxf(vB0, vB1), fmaxf(vB2, vB3));
    mxA = fmaxf(mxA, __shfl_xor(mxA, 16)); mxA = fmaxf(mxA, __shfl_xor(mxA, 32));
    mxB = fmaxf(mxB, __shfl_xor(mxB, 16)); mxB = fmaxf(mxB, __shfl_xor(mxB, 32));
    float eA0 = __expf(vA0 - mxA), eA1 = __expf(vA1 - mxA);
    float eA2 = __expf(vA2 - mxA), eA3 = __expf(vA3 - mxA);
    float eB0 = __expf(vB0 - mxB), eB1 = __expf(vB1 - mxB);
    float eB2 = __expf(vB2 - mxB), eB3 = __expf(vB3 - mxB);
    float sA4 = eA0 + eA1 + eA2 + eA3;
    float sB4 = eB0 + eB1 + eB2 + eB3;
    sA4 += __shfl_xor(sA4, 16); sA4 += __shfl_xor(sA4, 32);
    sB4 += __shfl_xor(sB4, 16); sB4 += __shfl_xor(sB4, 32);
    float lsA = mxA + __logf(sA4), invA = 1.0f / sA4;
    float lsB = mxB + __logf(sB4), invB = 1.0f / sB4;
    float gA0 = vA0 - lsA, gA1 = vA1 - lsA, gA2 = vA2 - lsA, gA3 = vA3 - lsA;
    float gB0 = vB0 - lsB, gB1 = vB1 - lsB, gB2 = vB2 - lsB, gB3 = vB3 - lsB;
    float entA = gA0 * eA0 + gA1 * eA1 + gA2 * eA2 + gA3 * eA3;
    float entB = gB0 * eB0 + gB1 * eB1 + gB2 * eB2 + gB3 * eB3;
    entA += __shfl_xor(entA, 16); entA += __shfl_xor(entA, 32);
    entB += __shfl_xor(entB, 16); entB += __shfl_xor(entB, 32);
    if (tA >= 1) {
      *(float4*)&out[OFF_TRS + (size_t)(tA - 1) * 256 + n0] = make_float4(gA0, gA1, gA2, gA3);
      if (kb == 0) out[OFF_ENT + (size_t)(tA - 1) * 16 + nt] = -entA * invA;
    }
    *(float4*)&out[OFF_TRS + (size_t)(tB - 1) * 256 + n0] = make_float4(gB0, gB1, gB2, gB3);
    if (kb == 0) out[OFF_ENT + (size_t)(tB - 1) * 16 + nt] = -entB * invB;
  }
  // ---- t=0 cols 256..271 -> ws_logtr0 (raw; boundary softmaxes) ----
  if (tA == 0) {
    const int n0 = 256 + kb * 4;
    float4 b4 = *(const float4*)&ob3[n0];
    float4 v;
    #pragma unroll
    for (int r = 0; r < 4; ++r) (&v.x)[r] = accA[16][r] + (&b4.x)[r];
    *(float4*)&ws_logtr0[kb * 4] = v;
  }
}

// ---------------- Kernel 2: chunk fold, 4 parallel sub-chains + in-block combine ----------------
// Block c: chunk c (256 k's) split into 4 sub-chains of 64, one 256-thread group each.
// G[k][i][j] = trs[k][i][j] + pis[k+1][j]; sub-products combined by a 2-level tree.
extern "C" __global__ void __launch_bounds__(1024)
k_chunk(const float* __restrict__ out, float* __restrict__ Ms, float* __restrict__ MsT)
{
  __shared__ float Msh[2][4][256];
  __shared__ float Gsh[2][4][256];
  __shared__ float Sub[4][256];
  __shared__ float Pc[2][256];

  const int c = blockIdx.x, tid = threadIdx.x;
  const int group = tid >> 8, gtid = tid & 255;
  const int i = gtid >> 4, j = gtid & 15;
  const int kend = min(c * CLEN + CLEN, NK);
  const int ks0 = c * CLEN + group * 64;
  const int ksend = min(ks0 + 64, kend);
  const float* trs = out + OFF_TRS;
  const float* pis = out + OFF_PIS;

  float mij = trs[(size_t)ks0 * 256 + gtid] + pis[(size_t)(ks0 + 1) * 16 + j];
  float trp = 0.f, pip = 0.f;
  if (ks0 + 1 < ksend) {
    trp = trs[(size_t)(ks0 + 1) * 256 + gtid];
    pip = pis[(size_t)(ks0 + 2) * 16 + j];
  }
  for (int it = 1; it < 64; ++it) {
    const int k = ks0 + it;
    const bool act = k < ksend;                 // group-uniform
    const float graw = trp + pip;               // G[k] (garbage if !act)
    const int kn = k + 1;
    if (kn < ksend) {                           // 1-deep prefetch
      trp = trs[(size_t)kn * 256 + gtid];
      pip = pis[(size_t)(kn + 1) * 16 + j];
    }
    const int sel = it & 1;
    Msh[sel][group][gtid] = mij;
    Gsh[sel][group][gtid] = graw;
    __syncthreads();
    if (act) {
      float tq[16];
      #pragma unroll
      for (int q = 0; q < 16; ++q) tq[q] = Msh[sel][group][i * 16 + q] + Gsh[sel][group][q * 16 + j];
      float mx = tq[0];
      #pragma unroll
      for (int q = 1; q < 16; ++q) mx = fmaxf(mx, tq[q]);
      float ssum = 0.f;
      #pragma unroll
      for (int q = 0; q < 16; ++q) ssum += __expf(tq[q] - mx);
      mij = mx + __logf(ssum);
    }
  }

  Sub[group][gtid] = mij;
  __syncthreads();
  // tree combine: P0 = S0 (x) S1, P1 = S2 (x) S3, final = P0 (x) P1
  if (group < 2) {
    const float* A = Sub[group * 2];
    const float* B = Sub[group * 2 + 1];
    float tq[16];
    #pragma unroll
    for (int q = 0; q < 16; ++q) tq[q] = A[i * 16 + q] + B[q * 16 + j];
    float mx = tq[0];
    #pragma unroll
    for (int q = 1; q < 16; ++q) mx = fmaxf(mx, tq[q]);
    float ssum = 0.f;
    #pragma unroll
    for (int q = 0; q < 16; ++q) ssum += __expf(tq[q] - mx);
    Pc[group][gtid] = mx + __logf(ssum);
  }
  __syncthreads();
  if (group == 0) {
    float tq[16];
    #pragma unroll
    for (int q = 0; q < 16; ++q) tq[q] = Pc[0][i * 16 + q] + Pc[1][q * 16 + j];
    float mx = tq[0];
    #pragma unroll
    for (int q = 1; q < 16; ++q) mx = fmaxf(mx, tq[q]);
    float ssum = 0.f;
    #pragma unroll
    for (int q = 0; q < 16; ++q) ssum += __expf(tq[q] - mx);
    float m = mx + __logf(ssum);
    Ms[c * 256 + gtid] = m;
    MsT[c * 256 + j * 16 + i] = m;   // transposed for the alpha direction
  }
}

// ---------------- Kernel 3: boundary scan (1 wave per direction), 4-slot prefetch ----------------
extern "C" __global__ void __launch_bounds__(64)
k_boundary(const float* __restrict__ Ms, const float* __restrict__ MsT,
           const float* __restrict__ lt0, float* __restrict__ out,
           float* __restrict__ bA, float* __restrict__ bB)
{
  const int l = threadIdx.x;
  const int g = l >> 4;
  const int j = l & 15;
  if (blockIdx.x == 0) {
    // a0 = log_softmax(lt0) + log_pis[0]
    float ltp = lt0[j];
    float mx = ltp;
    #pragma unroll
    for (int d = 1; d < 16; d <<= 1) mx = fmaxf(mx, __shfl_xor(mx, d));
    float sm = __expf(ltp - mx);
    #pragma unroll
    for (int d = 1; d < 16; d <<= 1) sm += __shfl_xor(sm, d);
    float ls = mx + __logf(sm);
    float a0p = ltp - ls + out[OFF_PIS + j];
    if (l < 16) { bA[l] = a0p; out[OFF_ALPHA + l] = a0p; }
    float v0 = __shfl(a0p, g * 4 + 0), v1 = __shfl(a0p, g * 4 + 1);
    float v2 = __shfl(a0p, g * 4 + 2), v3 = __shfl(a0p, g * 4 + 3);
    float4 sl[4];
    #pragma unroll
    for (int r = 0; r < 4; ++r)
      sl[r] = *(const float4*)&MsT[r * 256 + j * 16 + g * 4];
    for (int cb = 0; cb < NCH; cb += 4) {
      #pragma unroll
      for (int u = 0; u < 4; ++u) {
        const int c = cb + u;
        float4 mr = sl[u];
        float t0 = v0 + mr.x, t1 = v1 + mr.y, t2 = v2 + mr.z, t3 = v3 + mr.w;
        float m = fmaxf(fmaxf(t0, t1), fmaxf(t2, t3));
        float ssum = __expf(t0 - m) + __expf(t1 - m) + __expf(t2 - m) + __expf(t3 - m);
        lse_merge(m, ssum, __shfl_xor(m, 16), __shfl_xor(ssum, 16));
        lse_merge(m, ssum, __shfl_xor(m, 32), __shfl_xor(ssum, 32));
        float nv = m + __logf(ssum);
        if (c + 1 < NCH && l < 16) bA[(c + 1) * 16 + l] = nv;
        v0 = __shfl(nv, g * 4 + 0); v1 = __shfl(nv, g * 4 + 1);
        v2 = __shfl(nv, g * 4 + 2); v3 = __shfl(nv, g * 4 + 3);
        const int cn = c + 4;
        if (cn < NCH) sl[u] = *(const float4*)&MsT[cn * 256 + j * 16 + g * 4];
      }
    }
  } else {
    const int i = j;
    float w0 = 0.f, w1 = 0.f, w2 = 0.f, w3 = 0.f;
    if (l < 16) {
      bB[(NCH - 1) * 16 + l] = 0.f;
      out[OFF_BETA + (size_t)(TT - 1) * 16 + l] = 0.f;
    }
    float4 sl[4];
    #pragma unroll
    for (int r = 0; r < 4; ++r)
      sl[r] = *(const float4*)&Ms[(NCH - 1 - r) * 256 + i * 16 + g * 4];
    for (int cb = NCH - 1; cb >= 0; cb -= 4) {
      #pragma unroll
      for (int u = 0; u < 4; ++u) {
        const int c = cb - u;
        float4 mr = sl[u];
        float t0 = w0 + mr.x, t1 = w1 + mr.y, t2 = w2 + mr.z, t3 = w3 + mr.w;
        float m = fmaxf(fmaxf(t0, t1), fmaxf(t2, t3));
        float ssum = __expf(t0 - m) + __expf(t1 - m) + __expf(t2 - m) + __expf(t3 - m);
        lse_merge(m, ssum, __shfl_xor(m, 16), __shfl_xor(ssum, 16));
        lse_merge(m, ssum, __shfl_xor(m, 32), __shfl_xor(ssum, 32));
        float nw = m + __logf(ssum);
        if (c > 0 && l < 16) bB[(c - 1) * 16 + l] = nw;
        w0 = __shfl(nw, g * 4 + 0); w1 = __shfl(nw, g * 4 + 1);
        w2 = __shfl(nw, g * 4 + 2); w3 = __shfl(nw, g * 4 + 3);
        const int cn = c - 4;
        if (cn >= 0) sl[u] = *(const float4*)&Ms[cn * 256 + i * 16 + g * 4];
      }
    }
  }
}

// ---------------- Kernel 4: per-chunk replay, depth-8 rolling register prefetch ----------------
#define PD 8
extern "C" __global__ void __launch_bounds__(64)
k_replay(float* __restrict__ out, const float* __restrict__ bA, const float* __restrict__ bB)
{
  const int l = threadIdx.x;
  const int g = l >> 4;
  const float* trs = out + OFF_TRS;
  const float* pis = out + OFF_PIS;
  if (blockIdx.x < NCH) {
    const int c = blockIdx.x;
    const int k0 = c * CLEN, k1 = min(k0 + CLEN, NK) - 1;
    const int j = l & 15;
    float v0 = bA[c * 16 + g * 4 + 0], v1 = bA[c * 16 + g * 4 + 1];
    float v2 = bA[c * 16 + g * 4 + 2], v3 = bA[c * 16 + g * 4 + 3];
    float tp[PD][4];
    float pp[PD];
    #pragma unroll
    for (int r = 0; r < PD; ++r) {
      const int kk = min(k0 + r, k1);
      #pragma unroll
      for (int q = 0; q < 4; ++q) tp[r][q] = trs[(size_t)kk * 256 + (g * 4 + q) * 16 + j];
      pp[r] = pis[(size_t)(kk + 1) * 16 + j];
    }
    for (int kb2 = k0; kb2 <= k1; kb2 += PD) {
      #pragma unroll
      for (int u = 0; u < PD; ++u) {
        const int k = kb2 + u;
        if (k <= k1) {
          float t0 = v0 + tp[u][0], t1 = v1 + tp[u][1];
          float t2 = v2 + tp[u][2], t3 = v3 + tp[u][3];
          float m = fmaxf(fmaxf(t0, t1), fmaxf(t2, t3));
          float ssum = __expf(t0 - m) + __expf(t1 - m) + __expf(t2 - m) + __expf(t3 - m);
          lse_merge(m, ssum, __shfl_xor(m, 16), __shfl_xor(ssum, 16));
          lse_merge(m, ssum, __shfl_xor(m, 32), __shfl_xor(ssum, 32));
          float nv = m + __logf(ssum) + pp[u];
          if (l < 16) out[OFF_ALPHA + (size_t)(k + 1) * 16 + l] = nv;
          v0 = __shfl(nv, g * 4 + 0); v1 = __shfl(nv, g * 4 + 1);
          v2 = __shfl(nv, g * 4 + 2); v3 = __shfl(nv, g * 4 + 3);
          const int kn = k + PD;
          if (kn <= k1) {
            #pragma unroll
            for (int q = 0; q < 4; ++q) tp[u][q] = trs[(size_t)kn * 256 + (g * 4 + q) * 16 + j];
            pp[u] = pis[(size_t)(kn + 1) * 16 + j];
          }
        }
      }
    }
  } else {
    const int c = blockIdx.x - NCH;
    const int k0 = c * CLEN, k1 = min(k0 + CLEN, NK) - 1;
    const int i = l & 15;
    float w0 = bB[c * 16 + g * 4 + 0], w1 = bB[c * 16 + g * 4 + 1];
    float w2 = bB[c * 16 + g * 4 + 2], w3 = bB[c * 16 + g * 4 + 3];
    float4 t4[PD];
    float4 p4[PD];
    #pragma unroll
    for (int r = 0; r < PD; ++r) {
      const int kk = max(k1 - r, k0);
      t4[r] = *(const float4*)&trs[(size_t)kk * 256 + i * 16 + g * 4];
      p4[r] = *(const float4*)&pis[(size_t)(kk + 1) * 16 + g * 4];
    }
    for (int kb2 = k1; kb2 >= k0; kb2 -= PD) {
      #pragma unroll
      for (int u = 0; u < PD; ++u) {
        const int k = kb2 - u;
        if (k >= k0) {
          float t0 = w0 + t4[u].x + p4[u].x;
          float t1 = w1 + t4[u].y + p4[u].y;
          float t2 = w2 + t4[u].z + p4[u].z;
          float t3 = w3 + t4[u].w + p4[u].w;
          float m = fmaxf(fmaxf(t0, t1), fmaxf(t2, t3));
          float ssum = __expf(t0 - m) + __expf(t1 - m) + __expf(t2 - m) + __expf(t3 - m);
          lse_merge(m, ssum, __shfl_xor(m, 16), __shfl_xor(ssum, 16));
          lse_merge(m, ssum, __shfl_xor(m, 32), __shfl_xor(ssum, 32));
          float nw = m + __logf(ssum);
          if (l < 16) out[OFF_BETA + (size_t)k * 16 + l] = nw;
          w0 = __shfl(nw, g * 4 + 0); w1 = __shfl(nw, g * 4 + 1);
          w2 = __shfl(nw, g * 4 + 2); w3 = __shfl(nw, g * 4 + 3);
          const int kn = k - PD;
          if (kn >= k0) {
            t4[u] = *(const float4*)&trs[(size_t)kn * 256 + i * 16 + g * 4];
            p4[u] = *(const float4*)&pis[(size_t)(kn + 1) * 16 + g * 4];
          }
        }
      }
    }
  }
}

extern "C" void kernel_launch(void* const* d_in, const int* in_sizes, int n_in,
                              void* d_out, int out_size, void* d_ws, size_t ws_size,
                              hipStream_t stream)
{
  const float* s     = (const float*)d_in[0];
  const float* a_arr = (const float*)d_in[1];
  const float* pW1 = (const float*)d_in[2];
  const float* pb1 = (const float*)d_in[3];
  const float* pW2 = (const float*)d_in[4];
  const float* pb2 = (const float*)d_in[5];
  const float* pW3 = (const float*)d_in[6];
  const float* pb3 = (const float*)d_in[7];
  const float* oW1 = (const float*)d_in[8];
  const float* ob1 = (const float*)d_in[9];
  const float* oW2 = (const float*)d_in[10];
  const float* ob2 = (const float*)d_in[11];
  const float* oW3 = (const float*)d_in[12];
  const float* ob3 = (const float*)d_in[13];
  const float* a_log_std = (const float*)d_in[14];
  float* out = (float*)d_out;

  // ws float region: Ms[65536] | MsT[65536] | bA[4096] | bB[4096] | (gap) | logtr0[16]
  float* wsf = (float*)d_ws;
  float* Ms  = wsf;
  float* MsT = wsf + 65536;
  float* bA  = wsf + 131072;
  float* bB  = wsf + 135168;
  float* lt0 = wsf + 139280;
  unsigned short* wbase = (unsigned short*)((char*)d_ws + WS_WEIGHT_OFF);

  k_wconv<<<(W_TOTAL + 255) / 256, 256, 0, stream>>>(pW1, pW2, pW3, oW1, oW2, oW3, wbase);
  k_mlp<<<TT / 128, 256, 0, stream>>>(s, a_arr, pb1, pb2, pb3, ob1, ob2, ob3,
                                      a_log_std, wbase, out, lt0);
  k_chunk<<<NCH, 1024, 0, stream>>>(out, Ms, MsT);
  k_boundary<<<2, 64, 0, stream>>>(Ms, MsT, lt0, out, bA, bB);
  k_replay<<<2 * NCH, 64, 0, stream>>>(out, bA, bB);
}